// Round 12
// baseline (236.868 us; speedup 1.0000x reference)
//
#include <hip/hip_runtime.h>

#define B_ 16
#define L_ 512
#define H_ 256
#define V_ 32000
#define HALF_ 128

typedef __attribute__((ext_vector_type(8))) short short8;
typedef __attribute__((ext_vector_type(4))) float floatx4;
typedef __attribute__((ext_vector_type(2))) float float2v;

__device__ __forceinline__ unsigned short f2bf(float x) {
  unsigned int u = __float_as_uint(x);
  unsigned int r = (u + 0x7FFFu + ((u >> 16) & 1u)) >> 16;
  return (unsigned short)r;
}

template <int CTRL>
__device__ __forceinline__ float dpp_xor_add(float x) {
  int y = __builtin_amdgcn_mov_dpp(__float_as_int(x), CTRL, 0xf, 0xf, true);
  return x + __int_as_float(y);
}

// butterfly sum over aligned 16-lane groups; ALL lanes get the result
__device__ __forceinline__ float redu16(float p) {
  p = dpp_xor_add<0xB1>(p);   // xor1
  p = dpp_xor_add<0x4E>(p);   // xor2
  p = dpp_xor_add<0x141>(p);  // row_half_mirror
  p = dpp_xor_add<0x140>(p);  // row_mirror
  return p;
}

// packed fp32 math (VOP3P)
__device__ __forceinline__ float2v pk_fma(float2v a, float2v b, float2v c) {
  float2v d;
  asm("v_pk_fma_f32 %0, %1, %2, %3" : "=v"(d) : "v"(a), "v"(b), "v"(c));
  return d;
}
__device__ __forceinline__ float2v pk_mul(float2v a, float2v b) {
  float2v d;
  asm("v_pk_mul_f32 %0, %1, %2" : "=v"(d) : "v"(a), "v"(b));
  return d;
}

// async global->LDS copy, 16B per lane, wave-uniform LDS base
__device__ __forceinline__ void async_cp16(const float* g, float* l) {
  __builtin_amdgcn_global_load_lds(
      (const __attribute__((address_space(1))) void*)g,
      (__attribute__((address_space(3))) void*)l, 16, 0, 0);
}

// load 8 fp32, convert to 8 bf16 packed in uint4
__device__ __forceinline__ uint4 load8cvt(const float* p) {
  float4 a = ((const float4*)p)[0];
  float4 b = ((const float4*)p)[1];
  uint4 r;
  r.x = (unsigned)f2bf(a.x) | ((unsigned)f2bf(a.y) << 16);
  r.y = (unsigned)f2bf(a.z) | ((unsigned)f2bf(a.w) << 16);
  r.z = (unsigned)f2bf(b.x) | ((unsigned)f2bf(b.y) << 16);
  r.w = (unsigned)f2bf(b.z) | ((unsigned)f2bf(b.w) << 16);
  return r;
}

// ---------------- GEMM1 (+weight conv blocks): a1 = relu(embed[seq] @ W1^T + b1) -> bf16 ----------------
// blocks 0..255: GEMM with gather + in-flight W1 conversion. blocks 256..447: convert W2/Wc -> bf16.
__global__ __launch_bounds__(256) void gemm1_kernel(const int* __restrict__ seq,
                                                    const float* __restrict__ embed,
                                                    const float* __restrict__ W1,
                                                    const float* __restrict__ b1,
                                                    const float* __restrict__ W2,
                                                    const float* __restrict__ Ws,
                                                    const float* __restrict__ We,
                                                    unsigned short* __restrict__ a1b,
                                                    unsigned short* __restrict__ W2b,
                                                    unsigned short* __restrict__ Wcb) {
  __shared__ unsigned short As[128 * 40];
  __shared__ unsigned short Bs[128 * 40];
  int blk = blockIdx.x;
  int tid = threadIdx.x;

  if (blk >= 256) {
    // weight conversion: 192 blocks x 1024 elements
    int base = (blk - 256) * 1024 + tid * 4;
    const float* src;
    unsigned short* dst;
    if (base < 131072) {
      src = W2 + base;
      dst = W2b + base;
    } else {
      int o = base - 131072;
      src = (o < 32768) ? (Ws + o) : (We + (o - 32768));
      dst = Wcb + o;
    }
    float4 v = *(const float4*)src;
    ushort4 o4;
    o4.x = f2bf(v.x); o4.y = f2bf(v.y); o4.z = f2bf(v.z); o4.w = f2bf(v.w);
    *(ushort4*)dst = o4;
    return;
  }

  int wave = tid >> 6, lane = tid & 63;
  int wm = (wave >> 1) * 64, wn = (wave & 1) * 64;
  int quad = lane >> 4, l15 = lane & 15;
  int bm = (blk >> 2) * 128, bn = (blk & 3) * 128;
  int sr = tid >> 2, sq = tid & 3;

  int tok0 = seq[bm + sr];
  int tok1 = seq[bm + 64 + sr];

  floatx4 zero = {0.f, 0.f, 0.f, 0.f};
  floatx4 acc[4][4];
#pragma unroll
  for (int fi = 0; fi < 4; fi++)
#pragma unroll
    for (int fj = 0; fj < 4; fj++) acc[fi][fj] = zero;

  uint4 av0 = load8cvt(embed + (size_t)tok0 * H_ + sq * 8);
  uint4 av1 = load8cvt(embed + (size_t)tok1 * H_ + sq * 8);
  uint4 bv0 = load8cvt(W1 + (size_t)(bn + sr) * 256 + sq * 8);
  uint4 bv1 = load8cvt(W1 + (size_t)(bn + 64 + sr) * 256 + sq * 8);

  for (int k0 = 0; k0 < 256; k0 += 32) {
    __syncthreads();
    *(uint4*)(As + sr * 40 + sq * 8) = av0;
    *(uint4*)(As + (64 + sr) * 40 + sq * 8) = av1;
    *(uint4*)(Bs + sr * 40 + sq * 8) = bv0;
    *(uint4*)(Bs + (64 + sr) * 40 + sq * 8) = bv1;
    __syncthreads();
    if (k0 + 32 < 256) {
      av0 = load8cvt(embed + (size_t)tok0 * H_ + k0 + 32 + sq * 8);
      av1 = load8cvt(embed + (size_t)tok1 * H_ + k0 + 32 + sq * 8);
      bv0 = load8cvt(W1 + (size_t)(bn + sr) * 256 + k0 + 32 + sq * 8);
      bv1 = load8cvt(W1 + (size_t)(bn + 64 + sr) * 256 + k0 + 32 + sq * 8);
    }
    short8 af[4], bf[4];
#pragma unroll
    for (int f = 0; f < 4; f++) {
      af[f] = *(const short8*)(As + (wm + f * 16 + l15) * 40 + quad * 8);
      bf[f] = *(const short8*)(Bs + (wn + f * 16 + l15) * 40 + quad * 8);
    }
#pragma unroll
    for (int fi = 0; fi < 4; fi++)
#pragma unroll
      for (int fj = 0; fj < 4; fj++)
        acc[fi][fj] = __builtin_amdgcn_mfma_f32_16x16x32_bf16(af[fi], bf[fj], acc[fi][fj], 0, 0, 0);
  }

#pragma unroll
  for (int fi = 0; fi < 4; fi++) {
#pragma unroll
    for (int fj = 0; fj < 4; fj++) {
      int col = bn + wn + fj * 16 + l15;
      float bb = b1[col];
#pragma unroll
      for (int rg = 0; rg < 4; rg++) {
        int row = bm + wm + fi * 16 + quad * 4 + rg;
        float v = fmaxf(acc[fi][fj][rg] + bb, 0.f);
        a1b[(size_t)row * 512 + col] = f2bf(v);
      }
    }
  }
}

// ---------------- MLPK: hn = LN(a1 @ W2^T + b2 + embed[seq]) [LDS]; kproj -> khat (coalesced) + nrm ----------------
__global__ __launch_bounds__(256) void mlpk_kernel(const unsigned short* __restrict__ a1b,
                                                   const unsigned short* __restrict__ W2b,
                                                   const float* __restrict__ b2,
                                                   const int* __restrict__ seq,
                                                   const float* __restrict__ embed,
                                                   const float* __restrict__ gamma,
                                                   const float* __restrict__ beta,
                                                   const unsigned short* __restrict__ Wcb,
                                                   float* __restrict__ khat,
                                                   float* __restrict__ nrm) {
  __shared__ unsigned short As[32 * 40];
  __shared__ unsigned short Bs[256 * 40];
  __shared__ unsigned short hnS[32 * 264];
  __shared__ float stats[2][2][32];
  __shared__ float stg[2][32 * 132];  // khat staging, padded rows
  int tid = threadIdx.x;
  int wave = tid >> 6, lane = tid & 63;
  int wm = (wave >> 1) * 16, wnh = wave & 1, wn = wnh * 128;
  int quad = lane >> 4, l15 = lane & 15;
  int bm = blockIdx.x * 32;
  int sr = tid >> 2, sq = tid & 3;

  floatx4 zero = {0.f, 0.f, 0.f, 0.f};
  floatx4 acc[8];
#pragma unroll
  for (int fj = 0; fj < 8; fj++) acc[fj] = zero;

  // -------- phase 1: a1 @ W2^T, K=512 --------
  uint4 av, bv[4];
  if (tid < 128) av = *(const uint4*)(a1b + (size_t)(bm + sr) * 512 + sq * 8);
#pragma unroll
  for (int q = 0; q < 4; q++) {
    int unit = q * 256 + tid;
    bv[q] = *(const uint4*)(W2b + (size_t)(unit >> 2) * 512 + (unit & 3) * 8);
  }
  for (int k0 = 0; k0 < 512; k0 += 32) {
    __syncthreads();
    if (tid < 128) *(uint4*)(As + sr * 40 + sq * 8) = av;
#pragma unroll
    for (int q = 0; q < 4; q++) {
      int unit = q * 256 + tid;
      *(uint4*)(Bs + (unit >> 2) * 40 + (unit & 3) * 8) = bv[q];
    }
    __syncthreads();
    if (k0 + 32 < 512) {
      if (tid < 128) av = *(const uint4*)(a1b + (size_t)(bm + sr) * 512 + k0 + 32 + sq * 8);
#pragma unroll
      for (int q = 0; q < 4; q++) {
        int unit = q * 256 + tid;
        bv[q] = *(const uint4*)(W2b + (size_t)(unit >> 2) * 512 + k0 + 32 + (unit & 3) * 8);
      }
    }
    short8 af = *(const short8*)(As + (wm + l15) * 40 + quad * 8);
    short8 bf[8];
#pragma unroll
    for (int fj = 0; fj < 8; fj++)
      bf[fj] = *(const short8*)(Bs + (wn + fj * 16 + l15) * 40 + quad * 8);
#pragma unroll
    for (int fj = 0; fj < 8; fj++)
      acc[fj] = __builtin_amdgcn_mfma_f32_16x16x32_bf16(af, bf[fj], acc[fj], 0, 0, 0);
  }

  // -------- LN epilogue -> hnS (LDS) --------
  int seqv[4];
#pragma unroll
  for (int rg = 0; rg < 4; rg++) seqv[rg] = seq[bm + wm + quad * 4 + rg];
  float v[8][4];
#pragma unroll
  for (int fj = 0; fj < 8; fj++) {
    int col = wn + fj * 16 + l15;
    float bb = b2[col];
#pragma unroll
    for (int rg = 0; rg < 4; rg++)
      v[fj][rg] = acc[fj][rg] + bb + embed[(size_t)seqv[rg] * H_ + col];
  }
  float s_[4], q_[4];
#pragma unroll
  for (int rg = 0; rg < 4; rg++) {
    float s = 0.f, q = 0.f;
#pragma unroll
    for (int fj = 0; fj < 8; fj++) {
      s += v[fj][rg];
      q += v[fj][rg] * v[fj][rg];
    }
    s_[rg] = redu16(s);
    q_[rg] = redu16(q);
  }
  if (l15 == 0) {
#pragma unroll
    for (int rg = 0; rg < 4; rg++) {
      int rlocal = wm + quad * 4 + rg;
      stats[wnh][0][rlocal] = s_[rg];
      stats[wnh][1][rlocal] = q_[rg];
    }
  }
  __syncthreads();
#pragma unroll
  for (int rg = 0; rg < 4; rg++) {
    int rlocal = wm + quad * 4 + rg;
    float sum = stats[0][0][rlocal] + stats[1][0][rlocal];
    float ssq = stats[0][1][rlocal] + stats[1][1][rlocal];
    float mu = sum * (1.f / H_);
    float var = ssq * (1.f / H_) - mu * mu;
    float inv = rsqrtf(var + 1e-5f);
#pragma unroll
    for (int fj = 0; fj < 8; fj++) {
      int col = wn + fj * 16 + l15;
      float y = (v[fj][rg] - mu) * inv * gamma[col] + beta[col];
      hnS[rlocal * 264 + col] = f2bf(y);
    }
  }
  __syncthreads();

  // -------- phase 2: kproj, K=256, A from hnS --------
  floatx4 acc2[8];
#pragma unroll
  for (int fj = 0; fj < 8; fj++) acc2[fj] = zero;
#pragma unroll
  for (int q = 0; q < 4; q++) {
    int unit = q * 256 + tid;
    bv[q] = *(const uint4*)(Wcb + (size_t)(unit >> 2) * 256 + (unit & 3) * 8);
  }
  for (int k0 = 0; k0 < 256; k0 += 32) {
    __syncthreads();
#pragma unroll
    for (int q = 0; q < 4; q++) {
      int unit = q * 256 + tid;
      *(uint4*)(Bs + (unit >> 2) * 40 + (unit & 3) * 8) = bv[q];
    }
    __syncthreads();
    if (k0 + 32 < 256) {
#pragma unroll
      for (int q = 0; q < 4; q++) {
        int unit = q * 256 + tid;
        bv[q] = *(const uint4*)(Wcb + (size_t)(unit >> 2) * 256 + k0 + 32 + (unit & 3) * 8);
      }
    }
    short8 af = *(const short8*)(hnS + (wm + l15) * 264 + k0 + quad * 8);
    short8 bf[8];
#pragma unroll
    for (int fj = 0; fj < 8; fj++)
      bf[fj] = *(const short8*)(Bs + (wn + fj * 16 + l15) * 40 + quad * 8);
#pragma unroll
    for (int fj = 0; fj < 8; fj++)
      acc2[fj] = __builtin_amdgcn_mfma_f32_16x16x32_bf16(af, bf[fj], acc2[fj], 0, 0, 0);
  }

  // -------- norm epilogue: nrm + khat (permuted cols) staged in LDS, coalesced global write --------
  int b = bm >> 9;
  int idxm = b * 2 + wnh;
  int tloc0 = (bm & 511) + wm + quad * 4;
  float inv[4], nr4[4];
#pragma unroll
  for (int rg = 0; rg < 4; rg++) {
    float ssq = 0.f;
#pragma unroll
    for (int fj = 0; fj < 8; fj++) ssq += acc2[fj][rg] * acc2[fj][rg];
    ssq = redu16(ssq);
    nr4[rg] = fmaxf(sqrtf(ssq), 1e-12f);
    inv[rg] = 1.f / nr4[rg];
  }
  if (l15 == 0) {
#pragma unroll
    for (int rg = 0; rg < 4; rg++) nrm[(size_t)idxm * L_ + tloc0 + rg] = nr4[rg];
  }
#pragma unroll
  for (int fj = 0; fj < 8; fj++) {
    int ch = fj * 16 + l15;             // logical col 0..127
    int j = ch >> 2, e = ch & 3;
    int pj = (j & 1) ? (16 + (j >> 1)) : (j >> 1);  // even granules first
    int pcol = pj * 4 + e;
    int trl = wm + quad * 4;
#pragma unroll
    for (int rg = 0; rg < 4; rg++)
      stg[wnh][(trl + rg) * 132 + pcol] = acc2[fj][rg] * inv[rg];
  }
  __syncthreads();
  // coalesced: 2 halves x 32 rows x 128 cols = 2048 float4, 8 per thread
#pragma unroll
  for (int f = 0; f < 8; f++) {
    int idx = f * 256 + tid;
    int w = idx >> 10, rem = idx & 1023;
    int tr = rem >> 5, l = rem & 31;
    float4 vv = *(float4*)&stg[w][tr * 132 + l * 4];
    int im = (bm >> 9) * 2 + w;
    *(float4*)&khat[((size_t)im * L_ + (bm & 511) + tr) * HALF_ + l * 4] = vv;
  }
}

// ---------------- scan: dual-row-per-lane ILP, LDS-staged khat, packed-fp32 ----------------
#define STEP2(KP, KH0, KH1, NR)                                          \
  do {                                                                   \
    float2v ta_ = pk_mul(a01, KP[0]);                                    \
    float2v tb_ = pk_mul(b01, KP[0]);                                    \
    ta_ = pk_fma(a23, KP[1], ta_);                                       \
    tb_ = pk_fma(b23, KP[1], tb_);                                       \
    ta_ = pk_fma(a45, KP[2], ta_);                                       \
    tb_ = pk_fma(b45, KP[2], tb_);                                       \
    ta_ = pk_fma(a67, KP[3], ta_);                                       \
    tb_ = pk_fma(b67, KP[3], tb_);                                       \
    float p0_ = ta_.x + ta_.y, p1_ = tb_.x + tb_.y;                      \
    p0_ = dpp_xor_add<0xB1>(p0_);  p1_ = dpp_xor_add<0xB1>(p1_);         \
    p0_ = dpp_xor_add<0x4E>(p0_);  p1_ = dpp_xor_add<0x4E>(p1_);         \
    p0_ = dpp_xor_add<0x141>(p0_); p1_ = dpp_xor_add<0x141>(p1_);        \
    p0_ = dpp_xor_add<0x140>(p0_); p1_ = dpp_xor_add<0x140>(p1_);        \
    float s0_ = (KH0) * (NR)-p0_;                                        \
    float s1_ = (KH1) * (NR)-p1_;                                        \
    float2v s0v_ = {s0_, s0_}, s1v_ = {s1_, s1_};                        \
    a01 = pk_fma(s0v_, KP[0], a01);  b01 = pk_fma(s1v_, KP[0], b01);     \
    a23 = pk_fma(s0v_, KP[1], a23);  b23 = pk_fma(s1v_, KP[1], b23);     \
    a45 = pk_fma(s0v_, KP[2], a45);  b45 = pk_fma(s1v_, KP[2], b45);     \
    a67 = pk_fma(s0v_, KP[3], a67);  b67 = pk_fma(s1v_, KP[3], b67);     \
  } while (0)

#define LOADPK(DST, PTR)                                                 \
  do {                                                                   \
    float4 a_ = *(const float4*)(PTR);                                   \
    float4 b_ = *(const float4*)((PTR) + 64);                            \
    DST[0] = (float2v){a_.x, a_.y};                                      \
    DST[1] = (float2v){a_.z, a_.w};                                      \
    DST[2] = (float2v){b_.x, b_.y};                                      \
    DST[3] = (float2v){b_.z, b_.w};                                      \
  } while (0)

__device__ __forceinline__ int permrow(int rr) {
  int jj = rr >> 2, ee = rr & 3;
  int pj = (jj & 1) ? (16 + (jj >> 1)) : (jj >> 1);
  return pj * 4 + ee;
}

__global__ __launch_bounds__(128) void scan_kernel(const float* __restrict__ khat,
                                                   const float* __restrict__ nrm,
                                                   float* __restrict__ c) {
  __shared__ float sk[2][64 * 128];  // 2 x 32 KB double buffer
  int bid = blockIdx.x;
  int idxm = bid & 31;
  int rg = bid >> 5;
  int b = idxm >> 1, mat = idxm & 1;
  const float* kh = khat + (size_t)idxm * L_ * HALF_;
  const float* np = nrm + (size_t)idxm * L_;

  int tid = threadIdx.x;  // 0..127 (2 waves)
  int wave = tid >> 6, lane = tid & 63;
  int seg = tid & 15;
  int rp_i = tid >> 4;  // 0..7
  int r0 = rg * 16 + rp_i;
  int r1 = r0 + 8;
  int prow0 = permrow(r0), prow1 = permrow(r1);

  float2v a01 = {0.f, 0.f}, a23 = {0.f, 0.f}, a45 = {0.f, 0.f}, a67 = {0.f, 0.f};
  float2v b01 = {0.f, 0.f}, b23 = {0.f, 0.f}, b45 = {0.f, 0.f}, b67 = {0.f, 0.f};

  // stage chunk 0 into buf 0: 32 slices of 256 floats, 2 waves
#pragma unroll
  for (int j = 0; j < 16; j++) {
    int slice = j * 2 + wave;
    async_cp16(kh + slice * 256 + lane * 4, &sk[0][slice * 256] + lane * 4);
  }
  __syncthreads();

  float4 nrn = *(const float4*)(np);  // norms, steps 0..3
  const float* lb = &sk[0][0] + seg * 4;
  const float* lk0 = &sk[0][0] + prow0;
  const float* lk1 = &sk[0][0] + prow1;

  // chunks 0..6 (full 64 steps each)
  for (int ch = 0; ch < 7; ch++) {
#pragma unroll
    for (int j = 0; j < 16; j++) {
      int slice = j * 2 + wave;
      async_cp16(kh + (size_t)(ch + 1) * 8192 + slice * 256 + lane * 4,
                 &sk[(ch + 1) & 1][slice * 256] + lane * 4);
    }
    const float* base = lb + (ch & 1) * 8192;
    const float* ka2 = lk0 + (ch & 1) * 8192;
    const float* kb2 = lk1 + (ch & 1) * 8192;
    float2v pk[4][4];
    float kh4a[4], kh4b[4];
#pragma unroll
    for (int u = 0; u < 4; u++) {
      LOADPK(pk[u], base + u * 128);
      kh4a[u] = ka2[u * 128];
      kh4b[u] = kb2[u * 128];
    }
    for (int g = 0; g < 15; g++) {
      float4 nrc = nrn;
      nrn = *(const float4*)(np + ch * 64 + g * 4 + 4);
#pragma unroll
      for (int u = 0; u < 4; u++) {
        STEP2(pk[u], kh4a[u], kh4b[u],
              ((u == 0) ? nrc.x : (u == 1) ? nrc.y : (u == 2) ? nrc.z : nrc.w));
        int tn = g * 4 + u + 4;
        LOADPK(pk[u], base + tn * 128);
        kh4a[u] = ka2[tn * 128];
        kh4b[u] = kb2[tn * 128];
      }
    }
    {
      float4 nrc = nrn;
      nrn = *(const float4*)(np + ch * 64 + 64);
      STEP2(pk[0], kh4a[0], kh4b[0], nrc.x);
      STEP2(pk[1], kh4a[1], kh4b[1], nrc.y);
      STEP2(pk[2], kh4a[2], kh4b[2], nrc.z);
      STEP2(pk[3], kh4a[3], kh4b[3], nrc.w);
    }
    __syncthreads();
  }

  // chunk 7: steps 448..510, then query t=511 (left in pk[3])
  {
    const float* base = lb + 8192;
    const float* ka2 = lk0 + 8192;
    const float* kb2 = lk1 + 8192;
    float2v pk[4][4];
    float kh4a[4], kh4b[4];
#pragma unroll
    for (int u = 0; u < 4; u++) {
      LOADPK(pk[u], base + u * 128);
      kh4a[u] = ka2[u * 128];
      kh4b[u] = kb2[u * 128];
    }
    for (int g = 0; g < 15; g++) {
      float4 nrc = nrn;
      nrn = *(const float4*)(np + 448 + g * 4 + 4);
#pragma unroll
      for (int u = 0; u < 4; u++) {
        STEP2(pk[u], kh4a[u], kh4b[u],
              ((u == 0) ? nrc.x : (u == 1) ? nrc.y : (u == 2) ? nrc.z : nrc.w));
        int tn = g * 4 + u + 4;
        LOADPK(pk[u], base + tn * 128);
        kh4a[u] = ka2[tn * 128];
        kh4b[u] = kb2[tn * 128];
      }
    }
    float4 nrc = nrn;  // norms for 508..511
    STEP2(pk[0], kh4a[0], kh4b[0], nrc.x);  // 508
    STEP2(pk[1], kh4a[1], kh4b[1], nrc.y);  // 509
    STEP2(pk[2], kh4a[2], kh4b[2], nrc.z);  // 510
    // final read: q = khat[511]*nrm[511]; dot(M,q) = nrm511 * dot(m, khat511)
    float2v ta = pk_mul(a01, pk[3][0]);
    float2v tb = pk_mul(b01, pk[3][0]);
    ta = pk_fma(a23, pk[3][1], ta);
    tb = pk_fma(b23, pk[3][1], tb);
    ta = pk_fma(a45, pk[3][2], ta);
    tb = pk_fma(b45, pk[3][2], tb);
    ta = pk_fma(a67, pk[3][3], ta);
    tb = pk_fma(b67, pk[3][3], tb);
    float p0 = redu16(ta.x + ta.y) * nrc.w;
    float p1 = redu16(tb.x + tb.y) * nrc.w;
    if (seg == 0) {
      c[(size_t)b * H_ + mat * HALF_ + r0] = p0;
      c[(size_t)b * H_ + mat * HALF_ + r1] = p1;
    }
  }
}

// ---------------- r = c @ W_rp^T + b_rp ----------------
__global__ void rp_kernel(const float* __restrict__ c, const float* __restrict__ Wrp,
                          const float* __restrict__ brp, float* __restrict__ r) {
  int b = blockIdx.x;
  int n = threadIdx.x;  // 256
  __shared__ float cs[H_];
  cs[n] = c[(size_t)b * H_ + n];
  __syncthreads();
  const float4* w4 = (const float4*)(Wrp + (size_t)n * H_);
  const float4* c4 = (const float4*)cs;
  float acc = 0.f;
#pragma unroll 8
  for (int k = 0; k < H_ / 4; k++) {
    float4 w = w4[k], cc = c4[k];
    acc += w.x * cc.x + w.y * cc.y + w.z * cc.z + w.w * cc.w;
  }
  r[(size_t)b * H_ + n] = acc + brp[n];
}

// ---------------- out = r @ W_out^T + b_out, coalesced ----------------
__global__ __launch_bounds__(256) void out_kernel(const float* __restrict__ r,
                                                  const float* __restrict__ Wout,
                                                  const float* __restrict__ bout,
                                                  float* __restrict__ out) {
  __shared__ float rs[16 * 272];
  __shared__ float obuf[16 * 68];
  int tid = threadIdx.x;
#pragma unroll
  for (int q = 0; q < 16; q++) {
    int idx = q * 256 + tid;
    int bb = idx >> 8, cc = idx & 255;
    rs[bb * 272 + cc + 4 * (cc >> 6)] = r[idx];
  }
  __syncthreads();
  int row = tid >> 2, part = tid & 3;
  int v = blockIdx.x * 64 + row;
  const float4* w4 = (const float4*)(Wout + (size_t)v * H_ + part * 64);
  float acc[16];
#pragma unroll
  for (int bb = 0; bb < 16; bb++) acc[bb] = 0.f;
#pragma unroll 4
  for (int j = 0; j < 16; j++) {
    float4 w = w4[j];
#pragma unroll
    for (int bb = 0; bb < 16; bb++) {
      float4 rv = *(const float4*)&rs[bb * 272 + part * 68 + j * 4];
      acc[bb] += w.x * rv.x + w.y * rv.y + w.z * rv.z + w.w * rv.w;
    }
  }
  float bo = bout[v];
#pragma unroll
  for (int bb = 0; bb < 16; bb++) {
    acc[bb] = dpp_xor_add<0xB1>(acc[bb]);
    acc[bb] = dpp_xor_add<0x4E>(acc[bb]);
  }
#pragma unroll
  for (int q = 0; q < 4; q++) {
    int bb = part * 4 + q;
    obuf[bb * 68 + row] = acc[bb] + bo;
  }
  __syncthreads();
#pragma unroll
  for (int q = 0; q < 4; q++) {
    int idx = q * 256 + tid;
    int bb = idx >> 6, vl = idx & 63;
    out[(size_t)bb * V_ + blockIdx.x * 64 + vl] = obuf[bb * 68 + vl];
  }
}

extern "C" void kernel_launch(void* const* d_in, const int* in_sizes, int n_in,
                              void* d_out, int out_size, void* d_ws, size_t ws_size,
                              hipStream_t stream) {
  const int* seq = (const int*)d_in[0];
  const float* embed = (const float*)d_in[1];
  const float* W1 = (const float*)d_in[2];
  const float* b1 = (const float*)d_in[3];
  const float* W2 = (const float*)d_in[4];
  const float* b2 = (const float*)d_in[5];
  const float* gamma = (const float*)d_in[6];
  const float* beta = (const float*)d_in[7];
  const float* Wsem = (const float*)d_in[8];
  const float* Wepi = (const float*)d_in[9];
  const float* Wrp = (const float*)d_in[10];
  const float* brp = (const float*)d_in[11];
  const float* Wout = (const float*)d_in[12];
  const float* bout = (const float*)d_in[13];
  float* out = (float*)d_out;

  // Workspace (float-slot offsets), disjoint:
  //  [0       , 2097152)  a1b bf16 [8192,512]
  //  [2097152 , 4194304)  khat fp32 [32,512,128]
  //  [4194304 , 4210688)  nrm  fp32 [32,512]
  //  [4210688 , 4276224)  W2b bf16 131072
  //  [4276224 , 4308992)  Wcb bf16 65536
  //  [4308992 , 4313088)  c [16,256]
  //  [4313088 , 4317184)  r [16,256]
  float* ws = (float*)d_ws;
  unsigned short* a1b = (unsigned short*)ws;
  float* khat = ws + 2097152;
  float* nrm = ws + 4194304;
  unsigned short* W2b = (unsigned short*)(ws + 4210688);
  unsigned short* Wcb = (unsigned short*)(ws + 4276224);
  float* c = ws + 4308992;
  float* r = ws + 4313088;

  // 1. a1 = relu(embed[seq] @ W1^T + b1) -> bf16 ; extra blocks convert W2/Wc -> bf16
  gemm1_kernel<<<448, 256, 0, stream>>>(seq, embed, W1, b1, W2, Wsem, Wepi, a1b, W2b, Wcb);
  // 2. hn = LN(a1 @ W2^T + b2 + embed[seq]) [LDS]; kproj + normalize -> khat (coalesced) + nrm
  mlpk_kernel<<<256, 256, 0, stream>>>(a1b, W2b, b2, seq, embed, gamma, beta, Wcb, khat, nrm);
  // 3. delta-rule scan -> c [16,256]  (dual-row ILP, 2 waves/block)
  scan_kernel<<<256, 128, 0, stream>>>(khat, nrm, c);
  // 4. r = c @ Wrp^T + brp
  rp_kernel<<<16, 256, 0, stream>>>(c, Wrp, brp, r);
  // 5. out = r @ Wout^T + bout
  out_kernel<<<500, 256, 0, stream>>>(r, Wout, bout, out);
}